// Round 9
// baseline (133.425 us; speedup 1.0000x reference)
//
#include <hip/hip_runtime.h>
#include <math.h>

typedef __bf16 bf16x8 __attribute__((ext_vector_type(8)));
typedef __bf16 bf16x2 __attribute__((ext_vector_type(2)));
typedef float f32x4 __attribute__((ext_vector_type(4)));

namespace {
constexpr int kB = 128, kS = 256, kD = 128, kH = 4;
constexpr float kEps = 1e-6f;
constexpr float kScale = 0.17677669529663687f;  // 1/sqrt(32)
constexpr float kNeg = -1000000000.0f;
constexpr size_t kSZ = (size_t)kB * kS * kD;    // 4,194,304
}

// ---------------------------------------------------------------------------
// Weight transpose + convert: Wt[l*4+mtx][n][k] = (bf16) W[l][k][n]
// ---------------------------------------------------------------------------
__global__ __launch_bounds__(256) void wtrans(
    const float* __restrict__ Wq, const float* __restrict__ Wk,
    const float* __restrict__ Wv, const float* __restrict__ Wo,
    __bf16* __restrict__ Wt)
{
    const int mtx = blockIdx.x & 3, l = blockIdx.x >> 2;
    const float* W = (mtx == 0 ? Wq : mtx == 1 ? Wk : mtx == 2 ? Wv : Wo) +
                     (size_t)l * kD * kD;
    __bf16* o = Wt + (size_t)blockIdx.x * kD * kD;
    for (int idx = threadIdx.x; idx < kD * kD; idx += 256) {
        const int k = idx >> 7, n = idx & 127;
        o[n * 128 + k] = (__bf16)W[idx];
    }
}

// ---------------------------------------------------------------------------
// Fused QKV GEMM, 64KB LDS: A tile + ONE W tile re-staged for each of Q,K,V.
// A source is f32 (layer 0) or bf16 (layer 1). (round-5/6 known-good body)
// ---------------------------------------------------------------------------
template <bool F32A>
__global__ __launch_bounds__(512, 4) void qkv_gemm(
    const void* __restrict__ Av, const __bf16* __restrict__ Wt,
    const float* __restrict__ bq, const float* __restrict__ bk,
    const float* __restrict__ bv, __bf16* __restrict__ Qb,
    __bf16* __restrict__ Kb, __bf16* __restrict__ Vb)
{
    __shared__ __bf16 As[128 * 128];
    __shared__ __bf16 Ws[128 * 128];

    const int t = threadIdx.x;
    const int w = t >> 6, l = t & 63, lo = l & 15, g = l >> 4;
    const size_t m0 = (size_t)blockIdx.x * 128;

#pragma unroll
    for (int p = 0; p < 4; ++p) {
        const int ci = p * 512 + t;
        const int row = ci >> 4, c = ci & 15;
        if constexpr (F32A) {
            const float* src = (const float*)Av + (m0 + row) * 128 + c * 8;
            const float4 a0 = *(const float4*)src;
            const float4 a1 = *(const float4*)(src + 4);
            bf16x8 o;
            o[0] = (__bf16)a0.x; o[1] = (__bf16)a0.y; o[2] = (__bf16)a0.z; o[3] = (__bf16)a0.w;
            o[4] = (__bf16)a1.x; o[5] = (__bf16)a1.y; o[6] = (__bf16)a1.z; o[7] = (__bf16)a1.w;
            *(bf16x8*)&As[row * 128 + (c ^ (row & 7)) * 8] = o;
        } else {
            *(bf16x8*)&As[row * 128 + (c ^ (row & 7)) * 8] =
                *(const bf16x8*)((const __bf16*)Av + (m0 + row) * 128 + c * 8);
        }
    }
#pragma unroll
    for (int p = 0; p < 4; ++p) {
        const int ci = p * 512 + t;
        const int row = ci >> 4, c = ci & 15;
        *(bf16x8*)&Ws[row * 128 + (c ^ (row & 7)) * 8] =
            *(const bf16x8*)(Wt + row * 128 + c * 8);
    }
    __syncthreads();

    bf16x8 av[4];
    {
        const int arow = w * 16 + lo;
#pragma unroll
        for (int ks = 0; ks < 4; ++ks)
            av[ks] = *(const bf16x8*)&As[arow * 128 + ((g + 4 * ks) ^ (arow & 7)) * 8];
    }

    const float* biases[3] = {bq, bk, bv};
    __bf16* outs[3] = {Qb, Kb, Vb};

#pragma unroll
    for (int m = 0; m < 3; ++m) {
        f32x4 acc[8];
#pragma unroll
        for (int ni = 0; ni < 8; ++ni) acc[ni] = f32x4{0.f, 0.f, 0.f, 0.f};
#pragma unroll
        for (int ks = 0; ks < 4; ++ks)
#pragma unroll
            for (int ni = 0; ni < 8; ++ni) {
                const int brow = ni * 16 + lo;
                const bf16x8 bv8 =
                    *(const bf16x8*)&Ws[brow * 128 + ((g + 4 * ks) ^ (brow & 7)) * 8];
                acc[ni] = __builtin_amdgcn_mfma_f32_16x16x32_bf16(av[ks], bv8, acc[ni], 0, 0, 0);
            }
#pragma unroll
        for (int ni = 0; ni < 8; ++ni) {
            const float bc = biases[m][ni * 16 + lo];
#pragma unroll
            for (int r = 0; r < 4; ++r)
                outs[m][(m0 + w * 16 + g * 4 + r) * 128 + ni * 16 + lo] =
                    (__bf16)(acc[ni][r] + bc);
        }
        if (m < 2) {
            __syncthreads();
#pragma unroll
            for (int p = 0; p < 4; ++p) {
                const int ci = p * 512 + t;
                const int row = ci >> 4, c = ci & 15;
                *(bf16x8*)&Ws[row * 128 + (c ^ (row & 7)) * 8] =
                    *(const bf16x8*)(Wt + (m + 1) * 16384 + row * 128 + c * 8);
            }
            __syncthreads();
        }
    }
}

// ---------------------------------------------------------------------------
// FUSED attention + O-projection + residual + LayerNorm1.
// Grid 256, STRIP-MAJOR: bid = strip*128 + b, so both strips of batch b land
// on the same XCD (128 % 8 == 0) -> second K/V read is an L2 hit (T1).
// 512 threads = 8 waves x 16 queries. T14 async-stage for next head's K/V.
// RESF32: residual source f32 (layer0) or bf16 (layer1).
// WEIGHTS: wave holding q=255 emits softmax rows; total_l1 = 1024 exactly.
// ---------------------------------------------------------------------------
template <int WEIGHTS, bool RESF32>
__global__ __launch_bounds__(512) void attn_oproj(
    const __bf16* __restrict__ Qb, const __bf16* __restrict__ Kb,
    const __bf16* __restrict__ Vb, const float* __restrict__ mask,
    const __bf16* __restrict__ Wo, const float* __restrict__ bo,
    const void* __restrict__ resid, const float* __restrict__ gamma,
    const float* __restrict__ beta, __bf16* __restrict__ O1,
    float* __restrict__ wout, float* __restrict__ l1out)
{
    __shared__ __bf16 Kls[256 * 32];   // [key][32], 4 chunks/row XOR-swizzled
    __shared__ __bf16 Vt[32][270];     // V^T [d][key]
    __shared__ __bf16 Pl[8][16 * 128]; // per-wave half-P, swizzled chunks
    __shared__ __bf16 Ctx[128 * 128];  // swizzled ctx tile
    __shared__ __bf16 Wos[128 * 128];  // swizzled Wo
    __shared__ float mb[256];

    const int t = threadIdx.x;
    const int w = t >> 6, l = t & 63, lo = l & 15, g = l >> 4;
    const int b = blockIdx.x & 127, strip = blockIdx.x >> 7;  // strip-major
    const size_t bbase = (size_t)b * 256 * 128;
    const int q0 = strip * 128 + w * 16;
    const int kswz = (lo ^ (lo >> 2)) & 3;

    // prefetch registers for K/V staging (T14)
    bf16x8 kpre[2], vpre[2];
    const int krow = t >> 2, kc = t & 3;          // K: 2 chunks/thread
    const int vkey = t >> 2, vd0 = (t & 3) << 3;  // V: 2 chunks/thread

    auto loadKV = [&](int h) {
#pragma unroll
        for (int p = 0; p < 2; ++p)
            kpre[p] = *(const bf16x8*)(Kb + bbase + (size_t)(p * 128 + krow) * 128 +
                                       h * 32 + kc * 8);
#pragma unroll
        for (int p = 0; p < 2; ++p)
            vpre[p] = *(const bf16x8*)(Vb + bbase + (size_t)(p * 128 + vkey) * 128 +
                                       h * 32 + vd0);
    };
    auto writeKV = [&]() {
#pragma unroll
        for (int p = 0; p < 2; ++p) {
            const int row = p * 128 + krow;
            const int sw = (kc ^ ((row ^ (row >> 2)) & 3)) << 3;
            *(bf16x8*)&Kls[row * 32 + sw] = kpre[p];
        }
#pragma unroll
        for (int p = 0; p < 2; ++p) {
            const int key = p * 128 + vkey;
#pragma unroll
            for (int i = 0; i < 8; ++i) Vt[vd0 + i][key] = vpre[p][i];
        }
    };

    // stage Wo once (swizzled)
#pragma unroll
    for (int p = 0; p < 4; ++p) {
        const int ci = p * 512 + t;
        const int row = ci >> 4, c = ci & 15;
        *(bf16x8*)&Wos[row * 128 + ((c ^ (row & 7)) << 3)] =
            *(const bf16x8*)(Wo + row * 128 + c * 8);
    }
    if (t < 256) mb[t] = mask[b * 256 + t] * kNeg;
    if (WEIGHTS && blockIdx.x == 0 && t == 0) l1out[0] = 1024.0f;

    // all 4 Q head-fragments up front
    bf16x8 qfr[4];
#pragma unroll
    for (int h = 0; h < 4; ++h)
        qfr[h] = *(const bf16x8*)(Qb + bbase + (size_t)(q0 + lo) * 128 + h * 32 + g * 8);

    loadKV(0);
    writeKV();
    __syncthreads();

#pragma unroll
    for (int h = 0; h < 4; ++h) {
        // S^T = K @ Q^T  (16 key-frags)
        f32x4 s[16];
#pragma unroll
        for (int f = 0; f < 16; ++f) {
            const bf16x8 kf =
                *(const bf16x8*)&Kls[(f * 16 + lo) * 32 + ((g ^ kswz) << 3)];
            s[f] = __builtin_amdgcn_mfma_f32_16x16x32_bf16(
                kf, qfr[h], f32x4{0.f, 0.f, 0.f, 0.f}, 0, 0, 0);
        }

        if (h < 3) loadKV(h + 1);  // T14: issue next head's K/V now

        float mx = -1e30f;
#pragma unroll
        for (int f = 0; f < 16; ++f) {
            const f32x4 mk = *(const f32x4*)&mb[f * 16 + g * 4];
#pragma unroll
            for (int r = 0; r < 4; ++r) {
                s[f][r] = s[f][r] * kScale + mk[r];
                mx = fmaxf(mx, s[f][r]);
            }
        }
        mx = fmaxf(mx, __shfl_xor(mx, 16, 64));
        mx = fmaxf(mx, __shfl_xor(mx, 32, 64));

        float ls = 0.f;
#pragma unroll
        for (int f = 0; f < 16; ++f)
#pragma unroll
            for (int r = 0; r < 4; ++r) {
                const float p = __expf(s[f][r] - mx);
                s[f][r] = p;
                ls += p;
            }
        ls += __shfl_xor(ls, 16, 64);
        ls += __shfl_xor(ls, 32, 64);

        if constexpr (WEIGHTS) {
            if (strip == 1 && w == 7 && lo == 15) {
                const float inv = 1.f / ls;
                float* wrow = wout + ((size_t)b * 4 + h) * 256;
#pragma unroll
                for (int f = 0; f < 16; ++f)
#pragma unroll
                    for (int r = 0; r < 4; ++r)
                        wrow[f * 16 + g * 4 + r] = s[f][r] * inv;
            }
        }

        // PV in two half-P passes (keys 0..127, 128..255)
        f32x4 o[2] = {f32x4{0.f, 0.f, 0.f, 0.f}, f32x4{0.f, 0.f, 0.f, 0.f}};
#pragma unroll
        for (int half = 0; half < 2; ++half) {
#pragma unroll
            for (int f = 0; f < 8; ++f) {
                const int ff = half * 8 + f;
#pragma unroll
                for (int pr = 0; pr < 2; ++pr) {
                    bf16x2 pk;
                    pk[0] = (__bf16)s[ff][2 * pr];
                    pk[1] = (__bf16)s[ff][2 * pr + 1];
                    const int e = f * 16 + 4 * g + 2 * pr;
                    const int addr =
                        lo * 128 + ((((e >> 3) ^ (lo & 7)) << 3) | (e & 7));
                    *(bf16x2*)&Pl[w][addr] = pk;
                }
            }
#pragma unroll
            for (int ks = 0; ks < 4; ++ks) {
                const int cc = ks * 4 + g;
                const bf16x8 pa =
                    *(const bf16x8*)&Pl[w][lo * 128 + ((cc ^ (lo & 7)) << 3)];
#pragma unroll
                for (int nf = 0; nf < 2; ++nf) {
                    const bf16x8 bv =
                        *(const bf16x8*)&Vt[nf * 16 + lo][(half * 4 + ks) * 32 + g * 8];
                    o[nf] = __builtin_amdgcn_mfma_f32_16x16x32_bf16(pa, bv, o[nf], 0, 0, 0);
                }
            }
        }

        // normalized ctx -> swizzled LDS tile (cols h*32..h*32+31)
#pragma unroll
        for (int r = 0; r < 4; ++r) {
            const float inv = 1.f / __shfl(ls, 4 * g + r, 64);
            const int crow = w * 16 + g * 4 + r;
#pragma unroll
            for (int nf = 0; nf < 2; ++nf) {
                const int col = h * 32 + nf * 16 + lo;
                const int chunk = (col >> 3) ^ (crow & 7);
                Ctx[crow * 128 + (chunk << 3) + (col & 7)] = (__bf16)(o[nf][r] * inv);
            }
        }
        if (h < 3) {
            __syncthreads();   // all Kls/Vt reads of head h complete
            writeKV();         // regs -> LDS for head h+1
            __syncthreads();
        }
        // (no barrier after h==3: oproj A-frags read only this wave's Ctx rows)
    }

    // ---- O-projection + residual + LN1 (wave = 16 rows) ----
    const size_t m0 = (size_t)b * 256 + strip * 128;
    f32x4 acc[8];
#pragma unroll
    for (int ni = 0; ni < 8; ++ni) acc[ni] = f32x4{0.f, 0.f, 0.f, 0.f};

    const int arow = w * 16 + lo;
#pragma unroll
    for (int ks = 0; ks < 4; ++ks) {
        const bf16x8 av =
            *(const bf16x8*)&Ctx[arow * 128 + (((g + 4 * ks) ^ (arow & 7)) << 3)];
#pragma unroll
        for (int ni = 0; ni < 8; ++ni) {
            const int brow = ni * 16 + lo;
            const bf16x8 bv8 =
                *(const bf16x8*)&Wos[brow * 128 + (((g + 4 * ks) ^ (brow & 7)) << 3)];
            acc[ni] = __builtin_amdgcn_mfma_f32_16x16x32_bf16(av, bv8, acc[ni], 0, 0, 0);
        }
    }

    float bcol[8], ga[8], be[8];
#pragma unroll
    for (int ni = 0; ni < 8; ++ni) {
        bcol[ni] = bo[ni * 16 + lo];
        ga[ni] = gamma[ni * 16 + lo];
        be[ni] = beta[ni * 16 + lo];
    }

    float vv[4][8];
    float s[4] = {0, 0, 0, 0}, s2[4] = {0, 0, 0, 0};
#pragma unroll
    for (int r = 0; r < 4; ++r) {
        const size_t mm = m0 + w * 16 + g * 4 + r;
#pragma unroll
        for (int ni = 0; ni < 8; ++ni) {
            float rv;
            if constexpr (RESF32)
                rv = ((const float*)resid)[mm * 128 + ni * 16 + lo];
            else
                rv = (float)((const __bf16*)resid)[mm * 128 + ni * 16 + lo];
            const float x = acc[ni][r] + bcol[ni] + rv;
            vv[r][ni] = x; s[r] += x; s2[r] += x * x;
        }
    }
#pragma unroll
    for (int r = 0; r < 4; ++r)
#pragma unroll
        for (int o = 1; o < 16; o <<= 1) {
            s[r] += __shfl_xor(s[r], o, 64);
            s2[r] += __shfl_xor(s2[r], o, 64);
        }
#pragma unroll
    for (int r = 0; r < 4; ++r) {
        const float mu = s[r] * (1.f / 128.f);
        const float var = s2[r] * (1.f / 128.f) - mu * mu;
        const float rs = rsqrtf(var + kEps);
        const size_t mm = m0 + w * 16 + g * 4 + r;
#pragma unroll
        for (int ni = 0; ni < 8; ++ni)
            O1[mm * 128 + ni * 16 + lo] =
                (__bf16)(ga[ni] * (vv[r][ni] - mu) * rs + be[ni]);
    }
}

// ---------------------------------------------------------------------------
// FUSED tree aggregation + residual + LayerNorm2. One block per batch.
// e[255][132] f32 in LDS. PER-WAVE tree: wave w owns feature cols
// [w*8, w*8+8); features are independent, so all 7 levels run with NO block
// barrier (intra-wave LDS RAW handled by lgkmcnt). Only 2 barriers total:
// post-stage and pre-LN. LN per row as before.
// ---------------------------------------------------------------------------
__global__ __launch_bounds__(1024) void tree_ln(
    const __bf16* __restrict__ o1, const float* __restrict__ gamma,
    const float* __restrict__ beta, float* __restrict__ xo,
    __bf16* __restrict__ xb, int wf32, int wbf16)
{
    __shared__ float e[255 * 132];
    const int b = blockIdx.x;
    const int t = threadIdx.x;
    const __bf16* ob = o1 + (size_t)b * 256 * 128;

    // stage 255 rows (4080 bf16x8 chunks) -> f32 LDS (coalesced)
#pragma unroll
    for (int p = 0; p < 4; ++p) {
        const int ci = p * 1024 + t;
        if (ci < 4080) {
            const int row = ci >> 4, c8 = (ci & 15) * 8;
            const bf16x8 v = *(const bf16x8*)(ob + ci * 8);
            float* dst = &e[row * 132 + c8];
#pragma unroll
            for (int i = 0; i < 8; ++i) dst[i] = (float)v[i];
        }
    }
    __syncthreads();

    // per-wave barrier-free tree: wave w -> cols w*8..w*8+7
    {
        const int wv = t >> 6, ln = t & 63;
        const int col = wv * 8 + (ln & 7);
        const int nsub = ln >> 3;  // node sub-index 0..7
        for (int lvl = 6; lvl >= 0; --lvl) {
            const int p0 = (1 << lvl) - 1;
            const int cnt = 1 << lvl;
            for (int base = 0; base < cnt; base += 8) {
                const int p = p0 + base + nsub;
                if (base + nsub < cnt) {
                    e[p * 132 + col] =
                        tanhf(e[(2 * p + 1) * 132 + col] + e[(2 * p + 2) * 132 + col]);
                }
            }
        }
    }
    __syncthreads();

    // y = out1 + tab; LayerNorm per row (wave per row, 2 cols/lane)
    const int wv = t >> 6, lane = t & 63;
    const float2 gv = *(const float2*)(gamma + lane * 2);
    const float2 bb = *(const float2*)(beta + lane * 2);
    for (int row = wv; row < 256; row += 16) {
        const int c = lane * 2;
        float y0, y1;
        if (row >= 127 && row < 255) {
            // leaf rows: e holds original out1; tab == out1
            y0 = 2.f * e[row * 132 + c];
            y1 = 2.f * e[row * 132 + c + 1];
        } else if (row < 127) {
            // internal: original out1 from global, tab from (overwritten) e
            const bf16x2 v = *(const bf16x2*)(ob + (size_t)row * 128 + c);
            y0 = (float)v[0] + e[row * 132 + c];
            y1 = (float)v[1] + e[row * 132 + c + 1];
        } else {  // row == 255: pass-through, tab == out1
            const bf16x2 v = *(const bf16x2*)(ob + (size_t)row * 128 + c);
            y0 = 2.f * (float)v[0];
            y1 = 2.f * (float)v[1];
        }
        float s = y0 + y1, s2 = y0 * y0 + y1 * y1;
#pragma unroll
        for (int o = 1; o < 64; o <<= 1) {
            s += __shfl_xor(s, o, 64);
            s2 += __shfl_xor(s2, o, 64);
        }
        const float mu = s * (1.f / 128.f);
        const float var = s2 * (1.f / 128.f) - mu * mu;
        const float rs = rsqrtf(var + kEps);
        const float r0 = gv.x * (y0 - mu) * rs + bb.x;
        const float r1 = gv.y * (y1 - mu) * rs + bb.y;
        const size_t off = ((size_t)b * 256 + row) * 128 + c;
        if (wf32) {
            float2 o2; o2.x = r0; o2.y = r1;
            *(float2*)(xo + off) = o2;
        }
        if (wbf16) {
            bf16x2 ob2; ob2[0] = (__bf16)r0; ob2[1] = (__bf16)r1;
            *(bf16x2*)(xb + off) = ob2;
        }
    }
}

// ---------------------------------------------------------------------------
extern "C" void kernel_launch(void* const* d_in, const int* in_sizes, int n_in,
                              void* d_out, int out_size, void* d_ws, size_t ws_size,
                              hipStream_t stream)
{
    (void)in_sizes; (void)n_in; (void)out_size; (void)ws_size;

    const float* x_in = (const float*)d_in[0];
    const float* mask = (const float*)d_in[1];
    const float* Wq = (const float*)d_in[5];
    const float* bq = (const float*)d_in[6];
    const float* Wk = (const float*)d_in[7];
    const float* bk = (const float*)d_in[8];
    const float* Wv = (const float*)d_in[9];
    const float* bv = (const float*)d_in[10];
    const float* Wo = (const float*)d_in[11];
    const float* bo = (const float*)d_in[12];
    const float* g1 = (const float*)d_in[13];
    const float* b1 = (const float*)d_in[14];
    const float* g2 = (const float*)d_in[15];
    const float* b2 = (const float*)d_in[16];

    float* out_x = (float*)d_out;
    float* out_l1 = out_x + kSZ;
    float* out_w = out_l1 + 1;

    char* wsb = (char*)d_ws;
    __bf16* Qb = (__bf16*)wsb;
    __bf16* Kb = (__bf16*)(wsb + 1 * kSZ * 2);
    __bf16* Vb = (__bf16*)(wsb + 2 * kSZ * 2);
    __bf16* O1 = (__bf16*)(wsb + 3 * kSZ * 2);
    __bf16* xb = (__bf16*)(wsb + 4 * kSZ * 2);
    __bf16* Wt = (__bf16*)(wsb + 5 * kSZ * 2);   // 8 * 16384 bf16

    wtrans<<<8, 256, 0, stream>>>(Wq, Wk, Wv, Wo, Wt);

    // ---- layer 0 (f32 x_in) ----
    qkv_gemm<true><<<256, 512, 0, stream>>>(x_in, Wt, bq, bk, bv, Qb, Kb, Vb);
    attn_oproj<0, true><<<256, 512, 0, stream>>>(Qb, Kb, Vb, mask,
                                                 Wt + 3 * kD * kD, bo,
                                                 x_in, g1, b1, O1,
                                                 nullptr, nullptr);
    tree_ln<<<128, 1024, 0, stream>>>(O1, g2, b2, nullptr, xb, 0, 1);

    // ---- layer 1 (bf16 xb) ----
    const __bf16* WtL = Wt + 4 * kD * kD;
    qkv_gemm<false><<<256, 512, 0, stream>>>(xb, WtL, bq + kD, bk + kD, bv + kD,
                                             Qb, Kb, Vb);
    attn_oproj<1, false><<<256, 512, 0, stream>>>(Qb, Kb, Vb, mask,
                                                  WtL + 3 * kD * kD, bo + kD,
                                                  xb, g1 + kD, b1 + kD, O1,
                                                  out_w, out_l1);
    tree_ln<<<128, 1024, 0, stream>>>(O1, g2 + kD, b2 + kD, out_x, nullptr, 1, 0);
}

// Round 11
// 127.581 us; speedup vs baseline: 1.0458x; 1.0458x over previous
//
#include <hip/hip_runtime.h>
#include <math.h>

typedef __bf16 bf16x8 __attribute__((ext_vector_type(8)));
typedef __bf16 bf16x2 __attribute__((ext_vector_type(2)));
typedef float f32x4 __attribute__((ext_vector_type(4)));

namespace {
constexpr int kB = 128, kS = 256, kD = 128, kH = 4;
constexpr float kEps = 1e-6f;
constexpr float kScale = 0.17677669529663687f;  // 1/sqrt(32)
constexpr float kNeg = -1000000000.0f;
constexpr float kLog2e = 1.4426950408889634f;
constexpr size_t kSZ = (size_t)kB * kS * kD;    // 4,194,304
}

// ---------------------------------------------------------------------------
// global->LDS async DMA, 16 B/lane (dest = wave-uniform base + lane*16).
// Source must be pre-swizzled so a LINEAR copy yields the swizzled LDS layout.
// ---------------------------------------------------------------------------
__device__ __forceinline__ void glds16(const void* g, void* l) {
    __builtin_amdgcn_global_load_lds(
        (const __attribute__((address_space(1))) unsigned int*)g,
        (__attribute__((address_space(3))) unsigned int*)l, 16, 0, 0);
}

// ---------------------------------------------------------------------------
// Weight transpose + convert + PRE-SWIZZLE:
// Wt[m][n*128 + ((k/8)^(n&7))*8 + k%8] = (bf16) W[m][k][n]
// so that a linear global->LDS copy reproduces the XOR-swizzled tile layout.
// ---------------------------------------------------------------------------
__global__ __launch_bounds__(256) void wtrans(
    const float* __restrict__ Wq, const float* __restrict__ Wk,
    const float* __restrict__ Wv, const float* __restrict__ Wo,
    __bf16* __restrict__ Wt)
{
    const int mtx = blockIdx.x & 3, l = blockIdx.x >> 2;
    const float* W = (mtx == 0 ? Wq : mtx == 1 ? Wk : mtx == 2 ? Wv : Wo) +
                     (size_t)l * kD * kD;
    __bf16* o = Wt + (size_t)blockIdx.x * kD * kD;
    for (int idx = threadIdx.x; idx < kD * kD; idx += 256) {
        const int k = idx >> 7, n = idx & 127;
        o[n * 128 + (((k >> 3) ^ (n & 7)) << 3) + (k & 7)] = (__bf16)W[idx];
    }
}

// ---------------------------------------------------------------------------
// Fused QKV GEMM, 64KB LDS, 2 blocks/CU. W tiles staged via async
// global_load_lds (pre-swizzled source) and PING-PONGED through the dead As
// buffer: W1 loads into As during m=0 compute, W2 into Ws during m=1 compute
// -> staging latency hidden under MFMA instead of exposed between barriers.
// ---------------------------------------------------------------------------
template <bool F32A>
__global__ __launch_bounds__(512, 4) void qkv_gemm(
    const void* __restrict__ Av, const __bf16* __restrict__ Wt,
    const float* __restrict__ bq, const float* __restrict__ bk,
    const float* __restrict__ bv, __bf16* __restrict__ Qb,
    __bf16* __restrict__ Kb, __bf16* __restrict__ Vb)
{
    __shared__ __bf16 As[128 * 128];
    __shared__ __bf16 Ws[128 * 128];

    const int t = threadIdx.x;
    const int w = t >> 6, l = t & 63, lo = l & 15, g = l >> 4;
    const size_t m0 = (size_t)blockIdx.x * 128;

    // async: W0 -> Ws (linear DMA of pre-swizzled tile)
#pragma unroll
    for (int it = 0; it < 4; ++it)
        glds16(Wt + (it * 8 + w) * 512 + l * 8, &Ws[(it * 8 + w) * 512]);

    // manual stage A (cvt f32->bf16 or bf16 copy), swizzled
#pragma unroll
    for (int p = 0; p < 4; ++p) {
        const int ci = p * 512 + t;
        const int row = ci >> 4, c = ci & 15;
        if constexpr (F32A) {
            const float* src = (const float*)Av + (m0 + row) * 128 + c * 8;
            const float4 a0 = *(const float4*)src;
            const float4 a1 = *(const float4*)(src + 4);
            bf16x8 o;
            o[0] = (__bf16)a0.x; o[1] = (__bf16)a0.y; o[2] = (__bf16)a0.z; o[3] = (__bf16)a0.w;
            o[4] = (__bf16)a1.x; o[5] = (__bf16)a1.y; o[6] = (__bf16)a1.z; o[7] = (__bf16)a1.w;
            *(bf16x8*)&As[row * 128 + (c ^ (row & 7)) * 8] = o;
        } else {
            *(bf16x8*)&As[row * 128 + (c ^ (row & 7)) * 8] =
                *(const bf16x8*)((const __bf16*)Av + (m0 + row) * 128 + c * 8);
        }
    }
    __syncthreads();   // A visible, W0 landed (vmcnt drained by barrier)

    // A-fragments once, reused across the 3 matrices
    bf16x8 av[4];
    {
        const int arow = w * 16 + lo;
#pragma unroll
        for (int ks = 0; ks < 4; ++ks)
            av[ks] = *(const bf16x8*)&As[arow * 128 + ((g + 4 * ks) ^ (arow & 7)) * 8];
    }
    __syncthreads();   // all waves done reading As -> As reusable as W buffer

    // async: W1 -> As (overlaps m=0 compute)
#pragma unroll
    for (int it = 0; it < 4; ++it)
        glds16(Wt + 16384 + (it * 8 + w) * 512 + l * 8, &As[(it * 8 + w) * 512]);

    const float* biases[3] = {bq, bk, bv};
    __bf16* outs[3] = {Qb, Kb, Vb};
    const __bf16* wbuf[3] = {Ws, As, Ws};

#pragma unroll
    for (int m = 0; m < 3; ++m) {
        const __bf16* wb = wbuf[m];
        f32x4 acc[8];
#pragma unroll
        for (int ni = 0; ni < 8; ++ni) acc[ni] = f32x4{0.f, 0.f, 0.f, 0.f};
#pragma unroll
        for (int ks = 0; ks < 4; ++ks)
#pragma unroll
            for (int ni = 0; ni < 8; ++ni) {
                const int brow = ni * 16 + lo;
                const bf16x8 bv8 =
                    *(const bf16x8*)&wb[brow * 128 + ((g + 4 * ks) ^ (brow & 7)) * 8];
                acc[ni] = __builtin_amdgcn_mfma_f32_16x16x32_bf16(av[ks], bv8, acc[ni], 0, 0, 0);
            }
#pragma unroll
        for (int ni = 0; ni < 8; ++ni) {
            const float bc = biases[m][ni * 16 + lo];
#pragma unroll
            for (int r = 0; r < 4; ++r)
                outs[m][(m0 + w * 16 + g * 4 + r) * 128 + ni * 16 + lo] =
                    (__bf16)(acc[ni][r] + bc);
        }
        if (m == 0) {
            __syncthreads();  // W1 landed; Ws free (all waves done with W0)
            // async: W2 -> Ws (overlaps m=1 compute from As)
#pragma unroll
            for (int it = 0; it < 4; ++it)
                glds16(Wt + 2 * 16384 + (it * 8 + w) * 512 + l * 8,
                       &Ws[(it * 8 + w) * 512]);
        } else if (m == 1) {
            __syncthreads();  // W2 landed
        }
    }
}

// ---------------------------------------------------------------------------
// FUSED attention + O-projection + residual + LayerNorm1.
// Grid 256 strip-major; 512 threads = 8 waves x 16 queries.
// Softmax: NO max-subtraction (logits LN-bounded, |s| << exp2 range) and
// direct exp2 with scale/mask folded to log2 domain -> ~40% fewer VALU ops.
// Wo staged via async global_load_lds at kernel start (consumed 4 heads
// later, fully hidden). T5 setprio around MFMA clusters.
// WEIGHTS: wave holding q=255 emits softmax rows; total_l1 = 1024 exactly.
// ---------------------------------------------------------------------------
template <int WEIGHTS, bool RESF32>
__global__ __launch_bounds__(512) void attn_oproj(
    const __bf16* __restrict__ Qb, const __bf16* __restrict__ Kb,
    const __bf16* __restrict__ Vb, const float* __restrict__ mask,
    const __bf16* __restrict__ Wo, const float* __restrict__ bo,
    const void* __restrict__ resid, const float* __restrict__ gamma,
    const float* __restrict__ beta, __bf16* __restrict__ O1,
    float* __restrict__ wout, float* __restrict__ l1out)
{
    __shared__ __bf16 Kls[256 * 32];   // [key][32], 4 chunks/row XOR-swizzled
    __shared__ __bf16 Vt[32][270];     // V^T [d][key]
    __shared__ __bf16 Pl[8][16 * 128]; // per-wave half-P, swizzled chunks
    __shared__ __bf16 Ctx[128 * 128];  // swizzled ctx tile
    __shared__ __bf16 Wos[128 * 128];  // swizzled Wo (async DMA)
    __shared__ float mb[256];

    const int t = threadIdx.x;
    const int w = t >> 6, l = t & 63, lo = l & 15, g = l >> 4;
    const int b = blockIdx.x & 127, strip = blockIdx.x >> 7;  // strip-major
    const size_t bbase = (size_t)b * 256 * 128;
    const int q0 = strip * 128 + w * 16;
    const int kswz = (lo ^ (lo >> 2)) & 3;

    // async: Wo -> Wos (pre-swizzled; consumed after the head loop)
#pragma unroll
    for (int it = 0; it < 4; ++it)
        glds16(Wo + (it * 8 + w) * 512 + l * 8, &Wos[(it * 8 + w) * 512]);

    // prefetch registers for K/V staging (T14)
    bf16x8 kpre[2], vpre[2];
    const int krow = t >> 2, kc = t & 3;
    const int vkey = t >> 2, vd0 = (t & 3) << 3;

    auto loadKV = [&](int h) {
#pragma unroll
        for (int p = 0; p < 2; ++p)
            kpre[p] = *(const bf16x8*)(Kb + bbase + (size_t)(p * 128 + krow) * 128 +
                                       h * 32 + kc * 8);
#pragma unroll
        for (int p = 0; p < 2; ++p)
            vpre[p] = *(const bf16x8*)(Vb + bbase + (size_t)(p * 128 + vkey) * 128 +
                                       h * 32 + vd0);
    };
    auto writeKV = [&]() {
#pragma unroll
        for (int p = 0; p < 2; ++p) {
            const int row = p * 128 + krow;
            const int sw = (kc ^ ((row ^ (row >> 2)) & 3)) << 3;
            *(bf16x8*)&Kls[row * 32 + sw] = kpre[p];
        }
#pragma unroll
        for (int p = 0; p < 2; ++p) {
            const int key = p * 128 + vkey;
#pragma unroll
            for (int i = 0; i < 8; ++i) Vt[vd0 + i][key] = vpre[p][i];
        }
    };

    // mask bias, pre-scaled to log2 domain: mb = mask * kNeg * log2e
    if (t < 256) mb[t] = mask[b * 256 + t] * (kNeg * kLog2e);
    if (WEIGHTS && blockIdx.x == 0 && t == 0) l1out[0] = 1024.0f;

    // all 4 Q head-fragments up front
    bf16x8 qfr[4];
#pragma unroll
    for (int h = 0; h < 4; ++h)
        qfr[h] = *(const bf16x8*)(Qb + bbase + (size_t)(q0 + lo) * 128 + h * 32 + g * 8);

    loadKV(0);
    writeKV();
    __syncthreads();

#pragma unroll
    for (int h = 0; h < 4; ++h) {
        // S^T = K @ Q^T  (16 key-frags)
        f32x4 s[16];
        __builtin_amdgcn_s_setprio(1);
#pragma unroll
        for (int f = 0; f < 16; ++f) {
            const bf16x8 kf =
                *(const bf16x8*)&Kls[(f * 16 + lo) * 32 + ((g ^ kswz) << 3)];
            s[f] = __builtin_amdgcn_mfma_f32_16x16x32_bf16(
                kf, qfr[h], f32x4{0.f, 0.f, 0.f, 0.f}, 0, 0, 0);
        }
        __builtin_amdgcn_s_setprio(0);

        if (h < 3) loadKV(h + 1);  // T14: issue next head's K/V now

        // p = exp2(s * scale*log2e + mask') ; no max-subtraction
        float ls = 0.f;
#pragma unroll
        for (int f = 0; f < 16; ++f) {
            const f32x4 mk = *(const f32x4*)&mb[f * 16 + g * 4];
#pragma unroll
            for (int r = 0; r < 4; ++r) {
                const float p = __builtin_amdgcn_exp2f(
                    s[f][r] * (kScale * kLog2e) + mk[r]);
                s[f][r] = p;
                ls += p;
            }
        }
        ls += __shfl_xor(ls, 16, 64);
        ls += __shfl_xor(ls, 32, 64);

        if constexpr (WEIGHTS) {
            if (strip == 1 && w == 7 && lo == 15) {
                const float inv = 1.f / ls;
                float* wrow = wout + ((size_t)b * 4 + h) * 256;
#pragma unroll
                for (int f = 0; f < 16; ++f)
#pragma unroll
                    for (int r = 0; r < 4; ++r)
                        wrow[f * 16 + g * 4 + r] = s[f][r] * inv;
            }
        }

        // PV in two half-P passes (keys 0..127, 128..255)
        f32x4 o[2] = {f32x4{0.f, 0.f, 0.f, 0.f}, f32x4{0.f, 0.f, 0.f, 0.f}};
#pragma unroll
        for (int half = 0; half < 2; ++half) {
#pragma unroll
            for (int f = 0; f < 8; ++f) {
                const int ff = half * 8 + f;
#pragma unroll
                for (int pr = 0; pr < 2; ++pr) {
                    bf16x2 pk;
                    pk[0] = (__bf16)s[ff][2 * pr];
                    pk[1] = (__bf16)s[ff][2 * pr + 1];
                    const int e = f * 16 + 4 * g + 2 * pr;
                    const int addr =
                        lo * 128 + ((((e >> 3) ^ (lo & 7)) << 3) | (e & 7));
                    *(bf16x2*)&Pl[w][addr] = pk;
                }
            }
            __builtin_amdgcn_s_setprio(1);
#pragma unroll
            for (int ks = 0; ks < 4; ++ks) {
                const int cc = ks * 4 + g;
                const bf16x8 pa =
                    *(const bf16x8*)&Pl[w][lo * 128 + ((cc ^ (lo & 7)) << 3)];
#pragma unroll
                for (int nf = 0; nf < 2; ++nf) {
                    const bf16x8 bv =
                        *(const bf16x8*)&Vt[nf * 16 + lo][(half * 4 + ks) * 32 + g * 8];
                    o[nf] = __builtin_amdgcn_mfma_f32_16x16x32_bf16(pa, bv, o[nf], 0, 0, 0);
                }
            }
            __builtin_amdgcn_s_setprio(0);
        }

        // normalized ctx -> swizzled LDS tile (cols h*32..h*32+31)
#pragma unroll
        for (int r = 0; r < 4; ++r) {
            const float inv = 1.f / __shfl(ls, 4 * g + r, 64);
            const int crow = w * 16 + g * 4 + r;
#pragma unroll
            for (int nf = 0; nf < 2; ++nf) {
                const int col = h * 32 + nf * 16 + lo;
                const int chunk = (col >> 3) ^ (crow & 7);
                Ctx[crow * 128 + (chunk << 3) + (col & 7)] = (__bf16)(o[nf][r] * inv);
            }
        }
        if (h < 3) {
            __syncthreads();   // all Kls/Vt reads of head h complete
            writeKV();         // regs -> LDS for head h+1
            __syncthreads();
        }
    }

    // ---- O-projection + residual + LN1 (wave = 16 rows) ----
    const size_t m0 = (size_t)b * 256 + strip * 128;
    f32x4 acc[8];
#pragma unroll
    for (int ni = 0; ni < 8; ++ni) acc[ni] = f32x4{0.f, 0.f, 0.f, 0.f};

    const int arow = w * 16 + lo;
#pragma unroll
    for (int ks = 0; ks < 4; ++ks) {
        const bf16x8 av =
            *(const bf16x8*)&Ctx[arow * 128 + (((g + 4 * ks) ^ (arow & 7)) << 3)];
#pragma unroll
        for (int ni = 0; ni < 8; ++ni) {
            const int brow = ni * 16 + lo;
            const bf16x8 bv8 =
                *(const bf16x8*)&Wos[brow * 128 + (((g + 4 * ks) ^ (brow & 7)) << 3)];
            acc[ni] = __builtin_amdgcn_mfma_f32_16x16x32_bf16(av, bv8, acc[ni], 0, 0, 0);
        }
    }

    float bcol[8], ga[8], be[8];
#pragma unroll
    for (int ni = 0; ni < 8; ++ni) {
        bcol[ni] = bo[ni * 16 + lo];
        ga[ni] = gamma[ni * 16 + lo];
        be[ni] = beta[ni * 16 + lo];
    }

    float vv[4][8];
    float s[4] = {0, 0, 0, 0}, s2[4] = {0, 0, 0, 0};
#pragma unroll
    for (int r = 0; r < 4; ++r) {
        const size_t mm = m0 + w * 16 + g * 4 + r;
#pragma unroll
        for (int ni = 0; ni < 8; ++ni) {
            float rv;
            if constexpr (RESF32)
                rv = ((const float*)resid)[mm * 128 + ni * 16 + lo];
            else
                rv = (float)((const __bf16*)resid)[mm * 128 + ni * 16 + lo];
            const float x = acc[ni][r] + bcol[ni] + rv;
            vv[r][ni] = x; s[r] += x; s2[r] += x * x;
        }
    }
#pragma unroll
    for (int r = 0; r < 4; ++r)
#pragma unroll
        for (int o = 1; o < 16; o <<= 1) {
            s[r] += __shfl_xor(s[r], o, 64);
            s2[r] += __shfl_xor(s2[r], o, 64);
        }
#pragma unroll
    for (int r = 0; r < 4; ++r) {
        const float mu = s[r] * (1.f / 128.f);
        const float var = s2[r] * (1.f / 128.f) - mu * mu;
        const float rs = rsqrtf(var + kEps);
        const size_t mm = m0 + w * 16 + g * 4 + r;
#pragma unroll
        for (int ni = 0; ni < 8; ++ni)
            O1[mm * 128 + ni * 16 + lo] =
                (__bf16)(ga[ni] * (vv[r][ni] - mu) * rs + be[ni]);
    }
}

// ---------------------------------------------------------------------------
// FUSED tree aggregation + residual + LayerNorm2 (round-7 known-good).
// ---------------------------------------------------------------------------
__global__ __launch_bounds__(1024) void tree_ln(
    const __bf16* __restrict__ o1, const float* __restrict__ gamma,
    const float* __restrict__ beta, float* __restrict__ xo,
    __bf16* __restrict__ xb, int wf32, int wbf16)
{
    __shared__ float e[255 * 132];
    const int b = blockIdx.x;
    const int t = threadIdx.x;
    const __bf16* ob = o1 + (size_t)b * 256 * 128;

#pragma unroll
    for (int p = 0; p < 4; ++p) {
        const int ci = p * 1024 + t;
        if (ci < 4080) {
            const int row = ci >> 4, c8 = (ci & 15) * 8;
            const bf16x8 v = *(const bf16x8*)(ob + ci * 8);
            float* dst = &e[row * 132 + c8];
#pragma unroll
            for (int i = 0; i < 8; ++i) dst[i] = (float)v[i];
        }
    }
    __syncthreads();

    {
        const int wv = t >> 6, ln = t & 63;
        const int col = wv * 8 + (ln & 7);
        const int nsub = ln >> 3;
        for (int lvl = 6; lvl >= 0; --lvl) {
            const int p0 = (1 << lvl) - 1;
            const int cnt = 1 << lvl;
            for (int base = 0; base < cnt; base += 8) {
                const int p = p0 + base + nsub;
                if (base + nsub < cnt) {
                    e[p * 132 + col] =
                        tanhf(e[(2 * p + 1) * 132 + col] + e[(2 * p + 2) * 132 + col]);
                }
            }
        }
    }
    __syncthreads();

    const int wv = t >> 6, lane = t & 63;
    const float2 gv = *(const float2*)(gamma + lane * 2);
    const float2 bb = *(const float2*)(beta + lane * 2);
    for (int row = wv; row < 256; row += 16) {
        const int c = lane * 2;
        float y0, y1;
        if (row >= 127 && row < 255) {
            y0 = 2.f * e[row * 132 + c];
            y1 = 2.f * e[row * 132 + c + 1];
        } else if (row < 127) {
            const bf16x2 v = *(const bf16x2*)(ob + (size_t)row * 128 + c);
            y0 = (float)v[0] + e[row * 132 + c];
            y1 = (float)v[1] + e[row * 132 + c + 1];
        } else {
            const bf16x2 v = *(const bf16x2*)(ob + (size_t)row * 128 + c);
            y0 = 2.f * (float)v[0];
            y1 = 2.f * (float)v[1];
        }
        float s = y0 + y1, s2 = y0 * y0 + y1 * y1;
#pragma unroll
        for (int o = 1; o < 64; o <<= 1) {
            s += __shfl_xor(s, o, 64);
            s2 += __shfl_xor(s2, o, 64);
        }
        const float mu = s * (1.f / 128.f);
        const float var = s2 * (1.f / 128.f) - mu * mu;
        const float rs = rsqrtf(var + kEps);
        const float r0 = gv.x * (y0 - mu) * rs + bb.x;
        const float r1 = gv.y * (y1 - mu) * rs + bb.y;
        const size_t off = ((size_t)b * 256 + row) * 128 + c;
        if (wf32) {
            float2 o2; o2.x = r0; o2.y = r1;
            *(float2*)(xo + off) = o2;
        }
        if (wbf16) {
            bf16x2 ob2; ob2[0] = (__bf16)r0; ob2[1] = (__bf16)r1;
            *(bf16x2*)(xb + off) = ob2;
        }
    }
}

// ---------------------------------------------------------------------------
extern "C" void kernel_launch(void* const* d_in, const int* in_sizes, int n_in,
                              void* d_out, int out_size, void* d_ws, size_t ws_size,
                              hipStream_t stream)
{
    (void)in_sizes; (void)n_in; (void)out_size; (void)ws_size;

    const float* x_in = (const float*)d_in[0];
    const float* mask = (const float*)d_in[1];
    const float* Wq = (const float*)d_in[5];
    const float* bq = (const float*)d_in[6];
    const float* Wk = (const float*)d_in[7];
    const float* bk = (const float*)d_in[8];
    const float* Wv = (const float*)d_in[9];
    const float* bv = (const float*)d_in[10];
    const float* Wo = (const float*)d_in[11];
    const float* bo = (const float*)d_in[12];
    const float* g1 = (const float*)d_in[13];
    const float* b1 = (const float*)d_in[14];
    const float* g2 = (const float*)d_in[15];
    const float* b2 = (const float*)d_in[16];

    float* out_x = (float*)d_out;
    float* out_l1 = out_x + kSZ;
    float* out_w = out_l1 + 1;

    char* wsb = (char*)d_ws;
    __bf16* Qb = (__bf16*)wsb;
    __bf16* Kb = (__bf16*)(wsb + 1 * kSZ * 2);
    __bf16* Vb = (__bf16*)(wsb + 2 * kSZ * 2);
    __bf16* O1 = (__bf16*)(wsb + 3 * kSZ * 2);
    __bf16* xb = (__bf16*)(wsb + 4 * kSZ * 2);
    __bf16* Wt = (__bf16*)(wsb + 5 * kSZ * 2);   // 8 * 16384 bf16, pre-swizzled

    wtrans<<<8, 256, 0, stream>>>(Wq, Wk, Wv, Wo, Wt);

    // ---- layer 0 (f32 x_in) ----
    qkv_gemm<true><<<256, 512, 0, stream>>>(x_in, Wt, bq, bk, bv, Qb, Kb, Vb);
    attn_oproj<0, true><<<256, 512, 0, stream>>>(Qb, Kb, Vb, mask,
                                                 Wt + 3 * kD * kD, bo,
                                                 x_in, g1, b1, O1,
                                                 nullptr, nullptr);
    tree_ln<<<128, 1024, 0, stream>>>(O1, g2, b2, nullptr, xb, 0, 1);

    // ---- layer 1 (bf16 xb) ----
    const __bf16* WtL = Wt + 4 * kD * kD;
    qkv_gemm<false><<<256, 512, 0, stream>>>(xb, WtL, bq + kD, bk + kD, bv + kD,
                                             Qb, Kb, Vb);
    attn_oproj<1, false><<<256, 512, 0, stream>>>(Qb, Kb, Vb, mask,
                                                  WtL + 3 * kD * kD, bo + kD,
                                                  xb, g1 + kD, b1 + kD, O1,
                                                  out_w, out_l1);
    tree_ln<<<128, 1024, 0, stream>>>(O1, g2 + kD, b2 + kD, out_x, nullptr, 1, 0);
}